// Round 1
// baseline (1143.601 us; speedup 1.0000x reference)
//
#include <hip/hip_runtime.h>
#include <stdint.h>

#define N_TOK 16384
#define DIM   1024
#define NEXP  16
#define HID   4096

typedef unsigned short ushort_t;
typedef __bf16 bf16x8 __attribute__((ext_vector_type(8)));
typedef float  f32x4  __attribute__((ext_vector_type(4)));

// round-to-nearest-even fp32 -> bf16
__device__ __forceinline__ ushort_t f2bf(float f) {
    union { float f; unsigned int u; } v; v.f = f;
    unsigned int r = v.u + 0x7fffu + ((v.u >> 16) & 1u);
    return (ushort_t)(r >> 16);
}

__device__ __forceinline__ void gl_lds16(const void* g, void* l) {
    __builtin_amdgcn_global_load_lds(
        (const __attribute__((address_space(1))) void*)g,
        (__attribute__((address_space(3))) void*)l, 16, 0, 0);
}

// ---------------- cast x (fp32 -> bf16) ----------------
__global__ void __launch_bounds__(256) cast_x_kernel(const float* __restrict__ x,
                                                     ushort_t* __restrict__ xbf) {
    int i = (blockIdx.x * 256 + threadIdx.x) * 4;
    float4 v = *(const float4*)(x + i);
    ushort_t o0 = f2bf(v.x), o1 = f2bf(v.y), o2 = f2bf(v.z), o3 = f2bf(v.w);
    ushort4 o; o.x = o0; o.y = o1; o.z = o2; o.w = o3;
    *(ushort4*)(xbf + i) = o;
}

// ---------------- transpose+cast W1: [E][D][H] fp32 -> [E][H][D] bf16 ----------------
__global__ void __launch_bounds__(256) transpose_w1_kernel(const float* __restrict__ W1,
                                                           ushort_t* __restrict__ w1t) {
    __shared__ float tile[32][33];
    int e  = blockIdx.z;
    int h0 = blockIdx.x * 32;
    int d0 = blockIdx.y * 32;
    const float* src = W1 + (size_t)e * DIM * HID;
#pragma unroll
    for (int j = 0; j < 4; ++j) {
        int d = d0 + threadIdx.y + j * 8;
        tile[threadIdx.y + j * 8][threadIdx.x] = src[(size_t)d * HID + h0 + threadIdx.x];
    }
    __syncthreads();
    ushort_t* dst = w1t + (size_t)e * HID * DIM;
#pragma unroll
    for (int j = 0; j < 4; ++j) {
        int h = h0 + threadIdx.y + j * 8;
        dst[(size_t)h * DIM + d0 + threadIdx.x] = f2bf(tile[threadIdx.x][threadIdx.y + j * 8]);
    }
}

// ---------------- router: logits -> top2 -> softmax -> buckets; init out with gate*b2 ----------------
__global__ void __launch_bounds__(256) router_kernel(
    const float* __restrict__ x, const float* __restrict__ Wn,
    const float* __restrict__ bn, const float* __restrict__ b2,
    int* __restrict__ tok, float* __restrict__ gate, int* __restrict__ cnt,
    float* __restrict__ out) {
    int wave  = threadIdx.x >> 6;
    int lane  = threadIdx.x & 63;
    int token = blockIdx.x * 4 + wave;
    const float* xr = x + (size_t)token * DIM;
    float acc[NEXP];
#pragma unroll
    for (int e = 0; e < NEXP; ++e) acc[e] = 0.f;
    for (int d = lane; d < DIM; d += 64) {
        float xv = xr[d];
        const float* wr = Wn + d * NEXP;
#pragma unroll
        for (int e = 0; e < NEXP; ++e) acc[e] += xv * wr[e];
    }
#pragma unroll
    for (int e = 0; e < NEXP; ++e) {
        float v = acc[e];
#pragma unroll
        for (int off = 32; off > 0; off >>= 1) v += __shfl_xor(v, off, 64);
        acc[e] = v + bn[e];
    }
    if (lane == 0) {
        float m0 = -1e30f; int i0 = 0;
        for (int e = 0; e < NEXP; ++e) if (acc[e] > m0) { m0 = acc[e]; i0 = e; }
        float m1 = -1e30f; int i1 = 0;
        for (int e = 0; e < NEXP; ++e) if (e != i0 && acc[e] > m1) { m1 = acc[e]; i1 = e; }
        float tq = expf(m1 - m0);          // m1 <= m0, safe
        float p0 = 1.f / (1.f + tq);
        float p1 = 1.f - p0;
        int p = atomicAdd(&cnt[i0], 1);
        tok[i0 * N_TOK + p] = token; gate[i0 * N_TOK + p] = p0;
        p = atomicAdd(&cnt[i1], 1);
        tok[i1 * N_TOK + p] = token; gate[i1 * N_TOK + p] = p1;
        out[token] = p0 * b2[i0] + p1 * b2[i1];
    }
}

// ---------------- main: gathered expert FFN, bf16 MFMA 128x128xK tile ----------------
// grid: (HID/128, 64, NEXP), block 256
__global__ void __launch_bounds__(256, 2) moe_ffn_kernel(
    const ushort_t* __restrict__ xbf, const ushort_t* __restrict__ w1t,
    const float* __restrict__ b1, const float* __restrict__ w2,
    const int* __restrict__ tok, const float* __restrict__ gate,
    const int* __restrict__ cnt, float* __restrict__ out) {
    __shared__ ushort_t Alds[128 * 64];
    __shared__ ushort_t Blds[128 * 64];
    const int e  = blockIdx.z;
    const int ce = cnt[e];
    const int m0 = blockIdx.y * 128;
    if (m0 >= ce) return;
    const int h0 = blockIdx.x * 128;
    const int t    = threadIdx.x;
    const int wv   = t >> 6;
    const int lane = t & 63;
    const int quad = lane >> 4;
    const int ln   = lane & 15;
    const int wm   = (wv >> 1) * 64;   // wave M offset in tile
    const int wn   = (wv & 1) * 64;    // wave N offset in tile

    // Token ids for the A rows this thread stages (clamped into bucket; m0 < ce)
    int tkid[4];
#pragma unroll
    for (int i = 0; i < 4; ++i) {
        int f = i * 256 + t;
        int r = f >> 3;
        int rr = (m0 + r < ce) ? (m0 + r) : m0;
        tkid[i] = tok[e * N_TOK + rr];
    }

    f32x4 acc[4][4];
    const f32x4 zero = {0.f, 0.f, 0.f, 0.f};
#pragma unroll
    for (int mi = 0; mi < 4; ++mi)
#pragma unroll
        for (int ni = 0; ni < 4; ++ni) acc[mi][ni] = zero;

    for (int k0 = 0; k0 < DIM; k0 += 64) {
        // Stage A(128x64) and B(128x64, rows=h, cols=d) with XOR-swizzled 16B chunks.
        // LDS slot (r*8 + c) holds global k-chunk (c ^ (r&7)) of row r.
#pragma unroll
        for (int i = 0; i < 4; ++i) {
            int f = i * 256 + t;
            int r = f >> 3, c = f & 7;
            int cs = (c ^ (r & 7)) << 3;
            const ushort_t* ga = xbf + (size_t)tkid[i] * DIM + k0 + cs;
            gl_lds16(ga, &Alds[f * 8]);
            const ushort_t* gb = w1t + ((size_t)e * HID + h0 + r) * DIM + k0 + cs;
            gl_lds16(gb, &Blds[f * 8]);
        }
        __syncthreads();
#pragma unroll
        for (int ks = 0; ks < 2; ++ks) {
            int q = ks * 4 + quad;               // k-chunk index within row
            int csw = (q ^ (ln & 7)) << 3;       // swizzled element offset
            bf16x8 af[4], bfr[4];
#pragma unroll
            for (int mi = 0; mi < 4; ++mi)
                af[mi] = *(const bf16x8*)&Alds[(wm + mi * 16 + ln) * 64 + csw];
#pragma unroll
            for (int ni = 0; ni < 4; ++ni)
                bfr[ni] = *(const bf16x8*)&Blds[(wn + ni * 16 + ln) * 64 + csw];
#pragma unroll
            for (int mi = 0; mi < 4; ++mi)
#pragma unroll
                for (int ni = 0; ni < 4; ++ni)
                    acc[mi][ni] = __builtin_amdgcn_mfma_f32_16x16x32_bf16(
                        af[mi], bfr[ni], acc[mi][ni], 0, 0, 0);
        }
        __syncthreads();
    }

    // Epilogue: relu(acc + b1) * w2, reduce over the 64 h-columns this wave owns,
    // then atomicAdd gate*partial into out[token].
#pragma unroll
    for (int mi = 0; mi < 4; ++mi) {
        float part[4] = {0.f, 0.f, 0.f, 0.f};
#pragma unroll
        for (int ni = 0; ni < 4; ++ni) {
            int h = h0 + wn + ni * 16 + ln;
            float bb = b1[e * HID + h];
            float ww = w2[e * HID + h];
#pragma unroll
            for (int rg = 0; rg < 4; ++rg) {
                float v = acc[mi][ni][rg] + bb;
                v = v > 0.f ? v : 0.f;
                part[rg] += v * ww;
            }
        }
#pragma unroll
        for (int rg = 0; rg < 4; ++rg) {
            float v = part[rg];
            v += __shfl_xor(v, 1, 64);
            v += __shfl_xor(v, 2, 64);
            v += __shfl_xor(v, 4, 64);
            v += __shfl_xor(v, 8, 64);
            part[rg] = v;
        }
        if (ln == 0) {
#pragma unroll
            for (int rg = 0; rg < 4; ++rg) {
                int r = m0 + wm + mi * 16 + quad * 4 + rg;
                if (r < ce) {
                    int tk  = tok[e * N_TOK + r];
                    float g = gate[e * N_TOK + r];
                    atomicAdd(&out[tk], g * part[rg]);
                }
            }
        }
    }
}

extern "C" void kernel_launch(void* const* d_in, const int* in_sizes, int n_in,
                              void* d_out, int out_size, void* d_ws, size_t ws_size,
                              hipStream_t stream) {
    (void)in_sizes; (void)n_in; (void)out_size; (void)ws_size;
    const float* x  = (const float*)d_in[0];
    // d_in[1]=Wr, d_in[2]=br are dead in the reference
    const float* Wn = (const float*)d_in[3];
    const float* bn = (const float*)d_in[4];
    const float* W1 = (const float*)d_in[5];
    const float* b1 = (const float*)d_in[6];
    const float* W2 = (const float*)d_in[7];
    const float* b2 = (const float*)d_in[8];
    float* out = (float*)d_out;

    char* ws = (char*)d_ws;
    ushort_t* xbf = (ushort_t*)ws;                                     // 32 MB
    ushort_t* w1t = (ushort_t*)(ws + (size_t)32 * 1024 * 1024);        // 128 MB
    char* p2 = ws + (size_t)160 * 1024 * 1024;
    int*   tok  = (int*)p2;                                            // 1 MB
    float* gate = (float*)(p2 + (size_t)NEXP * N_TOK * 4);             // 1 MB
    int*   cnt  = (int*)(p2 + (size_t)2 * NEXP * N_TOK * 4);           // 64 B

    hipMemsetAsync(cnt, 0, NEXP * sizeof(int), stream);
    cast_x_kernel<<<N_TOK * DIM / 1024, 256, 0, stream>>>(x, xbf);
    transpose_w1_kernel<<<dim3(HID / 32, DIM / 32, NEXP), dim3(32, 8), 0, stream>>>(W1, w1t);
    router_kernel<<<N_TOK / 4, 256, 0, stream>>>(x, Wn, bn, b2, tok, gate, cnt, out);
    moe_ffn_kernel<<<dim3(HID / 128, 64, NEXP), 256, 0, stream>>>(xbf, w1t, b1, W2, tok,
                                                                  gate, cnt, out);
}

// Round 2
// 851.963 us; speedup vs baseline: 1.3423x; 1.3423x over previous
//
#include <hip/hip_runtime.h>
#include <stdint.h>

#define N_TOK 16384
#define DIM   1024
#define NEXP  16
#define HID   4096

typedef unsigned short ushort_t;
typedef __bf16 bf16x8 __attribute__((ext_vector_type(8)));
typedef float  f32x4  __attribute__((ext_vector_type(4)));

// round-to-nearest-even fp32 -> bf16
__device__ __forceinline__ ushort_t f2bf(float f) {
    union { float f; unsigned int u; } v; v.f = f;
    unsigned int r = v.u + 0x7fffu + ((v.u >> 16) & 1u);
    return (ushort_t)(r >> 16);
}

__device__ __forceinline__ void gl_lds16(const void* g, void* l) {
    __builtin_amdgcn_global_load_lds(
        (const __attribute__((address_space(1))) void*)g,
        (__attribute__((address_space(3))) void*)l, 16, 0, 0);
}

// ---------------- transpose+cast W1: [E][D][H] fp32 -> [E][H][D] bf16 ----------------
__global__ void __launch_bounds__(256) transpose_w1_kernel(const float* __restrict__ W1,
                                                           ushort_t* __restrict__ w1t) {
    __shared__ float tile[32][33];
    int e  = blockIdx.z;
    int h0 = blockIdx.x * 32;
    int d0 = blockIdx.y * 32;
    const float* src = W1 + (size_t)e * DIM * HID;
#pragma unroll
    for (int j = 0; j < 4; ++j) {
        int d = d0 + threadIdx.y + j * 8;
        tile[threadIdx.y + j * 8][threadIdx.x] = src[(size_t)d * HID + h0 + threadIdx.x];
    }
    __syncthreads();
    ushort_t* dst = w1t + (size_t)e * HID * DIM;
#pragma unroll
    for (int j = 0; j < 4; ++j) {
        int h = h0 + threadIdx.y + j * 8;
        dst[(size_t)h * DIM + d0 + threadIdx.x] = f2bf(tile[threadIdx.x][threadIdx.y + j * 8]);
    }
}

// ---------------- router: logits -> top2 -> per-token (eidx, probs); also emit xbf ----------------
// wave per token; NO atomics.
__global__ void __launch_bounds__(256) router_logits_kernel(
    const float* __restrict__ x, const float* __restrict__ Wn,
    const float* __restrict__ bn, const float* __restrict__ b2,
    ushort_t* __restrict__ xbf, int2* __restrict__ eidx,
    float2* __restrict__ probs, float* __restrict__ out) {
    int wave  = threadIdx.x >> 6;
    int lane  = threadIdx.x & 63;
    int token = blockIdx.x * 4 + wave;
    const float* xr = x + (size_t)token * DIM;
    float acc[NEXP];
#pragma unroll
    for (int e = 0; e < NEXP; ++e) acc[e] = 0.f;
    ushort_t xl[16];
#pragma unroll
    for (int i = 0; i < 16; ++i) {
        int d = lane + i * 64;
        float xv = xr[d];
        xl[i] = f2bf(xv);
        const float4* wr = (const float4*)(Wn + d * NEXP);
        float4 w0 = wr[0], w1 = wr[1], w2 = wr[2], w3 = wr[3];
        acc[0]  += xv * w0.x; acc[1]  += xv * w0.y; acc[2]  += xv * w0.z; acc[3]  += xv * w0.w;
        acc[4]  += xv * w1.x; acc[5]  += xv * w1.y; acc[6]  += xv * w1.z; acc[7]  += xv * w1.w;
        acc[8]  += xv * w2.x; acc[9]  += xv * w2.y; acc[10] += xv * w2.z; acc[11] += xv * w2.w;
        acc[12] += xv * w3.x; acc[13] += xv * w3.y; acc[14] += xv * w3.z; acc[15] += xv * w3.w;
    }
    ushort_t* xbr = xbf + (size_t)token * DIM;
#pragma unroll
    for (int i = 0; i < 16; ++i) xbr[lane + i * 64] = xl[i];
#pragma unroll
    for (int e = 0; e < NEXP; ++e) {
        float v = acc[e];
#pragma unroll
        for (int off = 32; off > 0; off >>= 1) v += __shfl_xor(v, off, 64);
        acc[e] = v + bn[e];
    }
    if (lane == 0) {
        float m0 = -1e30f; int i0 = 0;
        for (int e = 0; e < NEXP; ++e) if (acc[e] > m0) { m0 = acc[e]; i0 = e; }
        float m1 = -1e30f; int i1 = 0;
        for (int e = 0; e < NEXP; ++e) if (e != i0 && acc[e] > m1) { m1 = acc[e]; i1 = e; }
        float tq = expf(m1 - m0);          // m1 <= m0, safe
        float p0 = 1.f / (1.f + tq);
        float p1 = 1.f - p0;
        eidx[token]  = make_int2(i0, i1);
        probs[token] = make_float2(p0, p1);
        out[token]   = p0 * b2[i0] + p1 * b2[i1];
    }
}

// ---------------- bucket build: one block per expert, ballot+scan compaction ----------------
__global__ void __launch_bounds__(256) bucket_kernel(
    const int2* __restrict__ eidx, const float2* __restrict__ probs,
    int* __restrict__ tok, float* __restrict__ gate, int* __restrict__ cnt) {
    const int e = blockIdx.x;
    const int t = threadIdx.x;
    const int wv = t >> 6, lane = t & 63;
    __shared__ int wsum[4];
    __shared__ int sbase;
    if (t == 0) sbase = 0;
    __syncthreads();
    for (int t0 = 0; t0 < N_TOK; t0 += 256) {
        int token = t0 + t;
        int2  ei = eidx[token];
        float2 pr = probs[token];
        bool sel0 = (ei.x == e);
        bool sel  = sel0 | (ei.y == e);
        float p   = sel0 ? pr.x : pr.y;
        unsigned long long mask = __ballot(sel);
        int wprefix = __popcll(mask & ((1ull << lane) - 1ull));
        if (lane == 0) wsum[wv] = __popcll(mask);
        __syncthreads();
        int off = sbase + wprefix;
        for (int w = 0; w < wv; ++w) off += wsum[w];
        if (sel) {
            tok[e * N_TOK + off]  = token;
            gate[e * N_TOK + off] = p;
        }
        __syncthreads();
        if (t == 0) sbase += wsum[0] + wsum[1] + wsum[2] + wsum[3];
    }
    __syncthreads();
    if (t == 0) cnt[e] = sbase;
}

// ---------------- main: gathered expert FFN, bf16 MFMA 128x128xK tile ----------------
// grid: (HID/128, 64, NEXP), block 256
__global__ void __launch_bounds__(256, 2) moe_ffn_kernel(
    const ushort_t* __restrict__ xbf, const ushort_t* __restrict__ w1t,
    const float* __restrict__ b1, const float* __restrict__ w2,
    const int* __restrict__ tok, const float* __restrict__ gate,
    const int* __restrict__ cnt, float* __restrict__ out) {
    __shared__ ushort_t Alds[128 * 64];
    __shared__ ushort_t Blds[128 * 64];
    const int e  = blockIdx.z;
    const int ce = cnt[e];
    const int m0 = blockIdx.y * 128;
    if (m0 >= ce) return;
    const int h0 = blockIdx.x * 128;
    const int t    = threadIdx.x;
    const int wv   = t >> 6;
    const int lane = t & 63;
    const int quad = lane >> 4;
    const int ln   = lane & 15;
    const int wm   = (wv >> 1) * 64;   // wave M offset in tile
    const int wn   = (wv & 1) * 64;    // wave N offset in tile

    // Token ids for the A rows this thread stages (clamped into bucket; m0 < ce)
    int tkid[4];
#pragma unroll
    for (int i = 0; i < 4; ++i) {
        int f = i * 256 + t;
        int r = f >> 3;
        int rr = (m0 + r < ce) ? (m0 + r) : m0;
        tkid[i] = tok[e * N_TOK + rr];
    }

    f32x4 acc[4][4];
    const f32x4 zero = {0.f, 0.f, 0.f, 0.f};
#pragma unroll
    for (int mi = 0; mi < 4; ++mi)
#pragma unroll
        for (int ni = 0; ni < 4; ++ni) acc[mi][ni] = zero;

    for (int k0 = 0; k0 < DIM; k0 += 64) {
        // Stage A(128x64) and B(128x64, rows=h, cols=d) with XOR-swizzled 16B chunks.
        // LDS slot (r*8 + c) holds global k-chunk (c ^ (r&7)) of row r.
#pragma unroll
        for (int i = 0; i < 4; ++i) {
            int f = i * 256 + t;
            int r = f >> 3, c = f & 7;
            int cs = (c ^ (r & 7)) << 3;
            const ushort_t* ga = xbf + (size_t)tkid[i] * DIM + k0 + cs;
            gl_lds16(ga, &Alds[f * 8]);
            const ushort_t* gb = w1t + ((size_t)e * HID + h0 + r) * DIM + k0 + cs;
            gl_lds16(gb, &Blds[f * 8]);
        }
        __syncthreads();
#pragma unroll
        for (int ks = 0; ks < 2; ++ks) {
            int q = ks * 4 + quad;               // k-chunk index within row
            int csw = (q ^ (ln & 7)) << 3;       // swizzled element offset
            bf16x8 af[4], bfr[4];
#pragma unroll
            for (int mi = 0; mi < 4; ++mi)
                af[mi] = *(const bf16x8*)&Alds[(wm + mi * 16 + ln) * 64 + csw];
#pragma unroll
            for (int ni = 0; ni < 4; ++ni)
                bfr[ni] = *(const bf16x8*)&Blds[(wn + ni * 16 + ln) * 64 + csw];
#pragma unroll
            for (int mi = 0; mi < 4; ++mi)
#pragma unroll
                for (int ni = 0; ni < 4; ++ni)
                    acc[mi][ni] = __builtin_amdgcn_mfma_f32_16x16x32_bf16(
                        af[mi], bfr[ni], acc[mi][ni], 0, 0, 0);
        }
        __syncthreads();
    }

    // Epilogue: relu(acc + b1) * w2, reduce over the 64 h-columns this wave owns,
    // then atomicAdd gate*partial into out[token].
#pragma unroll
    for (int mi = 0; mi < 4; ++mi) {
        float part[4] = {0.f, 0.f, 0.f, 0.f};
#pragma unroll
        for (int ni = 0; ni < 4; ++ni) {
            int h = h0 + wn + ni * 16 + ln;
            float bb = b1[e * HID + h];
            float ww = w2[e * HID + h];
#pragma unroll
            for (int rg = 0; rg < 4; ++rg) {
                float v = acc[mi][ni][rg] + bb;
                v = v > 0.f ? v : 0.f;
                part[rg] += v * ww;
            }
        }
#pragma unroll
        for (int rg = 0; rg < 4; ++rg) {
            float v = part[rg];
            v += __shfl_xor(v, 1, 64);
            v += __shfl_xor(v, 2, 64);
            v += __shfl_xor(v, 4, 64);
            v += __shfl_xor(v, 8, 64);
            part[rg] = v;
        }
        if (ln == 0) {
#pragma unroll
            for (int rg = 0; rg < 4; ++rg) {
                int r = m0 + wm + mi * 16 + quad * 4 + rg;
                if (r < ce) {
                    int tk  = tok[e * N_TOK + r];
                    float g = gate[e * N_TOK + r];
                    atomicAdd(&out[tk], g * part[rg]);
                }
            }
        }
    }
}

extern "C" void kernel_launch(void* const* d_in, const int* in_sizes, int n_in,
                              void* d_out, int out_size, void* d_ws, size_t ws_size,
                              hipStream_t stream) {
    (void)in_sizes; (void)n_in; (void)out_size; (void)ws_size;
    const float* x  = (const float*)d_in[0];
    // d_in[1]=Wr, d_in[2]=br are dead in the reference
    const float* Wn = (const float*)d_in[3];
    const float* bn = (const float*)d_in[4];
    const float* W1 = (const float*)d_in[5];
    const float* b1 = (const float*)d_in[6];
    const float* W2 = (const float*)d_in[7];
    const float* b2 = (const float*)d_in[8];
    float* out = (float*)d_out;

    char* ws = (char*)d_ws;
    ushort_t* xbf = (ushort_t*)ws;                                     // 32 MB
    ushort_t* w1t = (ushort_t*)(ws + (size_t)32 * 1024 * 1024);        // 128 MB
    char* p2 = ws + (size_t)160 * 1024 * 1024;
    int*    tok   = (int*)p2;                                          // 1 MB
    float*  gate  = (float*)(p2 + (size_t)NEXP * N_TOK * 4);           // 1 MB
    int*    cnt   = (int*)(p2 + (size_t)2 * NEXP * N_TOK * 4);         // 64 B
    int2*   eidx  = (int2*)(p2 + (size_t)2 * NEXP * N_TOK * 4 + 256);  // 128 KB
    float2* probs = (float2*)(p2 + (size_t)2 * NEXP * N_TOK * 4 + 256 + (size_t)N_TOK * 8);

    transpose_w1_kernel<<<dim3(HID / 32, DIM / 32, NEXP), dim3(32, 8), 0, stream>>>(W1, w1t);
    router_logits_kernel<<<N_TOK / 4, 256, 0, stream>>>(x, Wn, bn, b2, xbf, eidx, probs, out);
    bucket_kernel<<<NEXP, 256, 0, stream>>>(eidx, probs, tok, gate, cnt);
    moe_ffn_kernel<<<dim3(HID / 128, 64, NEXP), 256, 0, stream>>>(xbf, w1t, b1, W2, tok,
                                                                  gate, cnt, out);
}

// Round 3
// 835.321 us; speedup vs baseline: 1.3691x; 1.0199x over previous
//
#include <hip/hip_runtime.h>
#include <stdint.h>

#define N_TOK 16384
#define DIM   1024
#define NEXP  16
#define HID   4096

typedef unsigned short ushort_t;
typedef __bf16 bf16x8 __attribute__((ext_vector_type(8)));
typedef float  f32x4  __attribute__((ext_vector_type(4)));
typedef ushort_t u16x8 __attribute__((ext_vector_type(8)));

// round-to-nearest-even fp32 -> bf16
__device__ __forceinline__ ushort_t f2bf(float f) {
    union { float f; unsigned int u; } v; v.f = f;
    unsigned int r = v.u + 0x7fffu + ((v.u >> 16) & 1u);
    return (ushort_t)(r >> 16);
}

__device__ __forceinline__ void gl_lds16(const void* g, void* l) {
    __builtin_amdgcn_global_load_lds(
        (const __attribute__((address_space(1))) void*)g,
        (__attribute__((address_space(3))) void*)l, 16, 0, 0);
}

// ---------------- transpose+cast W1: [E][D][H] fp32 -> [E][H][D] bf16 ----------------
// 64d x 64h tile per block. float4 reads (256B/row), 4x4 reg micro-transpose,
// LDS round-trip (stride 72 ushorts keeps 16B alignment), ushort8 stores
// (128B contiguous per h-row).
#define TS 72
__global__ void __launch_bounds__(256) transpose_w1_kernel(const float* __restrict__ W1,
                                                           ushort_t* __restrict__ w1t) {
    __shared__ ushort_t tileT[64 * TS];
    const int e  = blockIdx.z;
    const int h0 = blockIdx.x * 64;
    const int d0 = blockIdx.y * 64;
    const int t  = threadIdx.x;
    const int hs = t & 15;   // h-group of 4 floats
    const int dg = t >> 4;   // d-group of 4 rows
    const float* src = W1 + (size_t)e * DIM * HID;
    float4 rows[4];
#pragma unroll
    for (int i = 0; i < 4; ++i)
        rows[i] = *(const float4*)(src + (size_t)(d0 + dg * 4 + i) * HID + h0 + hs * 4);
#pragma unroll
    for (int j = 0; j < 4; ++j) {
        float v0 = (&rows[0].x)[j], v1 = (&rows[1].x)[j];
        float v2 = (&rows[2].x)[j], v3 = (&rows[3].x)[j];
        ushort4 col; col.x = f2bf(v0); col.y = f2bf(v1); col.z = f2bf(v2); col.w = f2bf(v3);
        *(ushort4*)&tileT[(hs * 4 + j) * TS + dg * 4] = col;
    }
    __syncthreads();
    ushort_t* dst = w1t + (size_t)e * HID * DIM;
#pragma unroll
    for (int p = 0; p < 2; ++p) {
        int r = p * 32 + (t >> 3);
        int c = t & 7;
        u16x8 fr = *(const u16x8*)&tileT[r * TS + c * 8];
        *(u16x8*)(dst + (size_t)(h0 + r) * DIM + d0 + c * 8) = fr;
    }
}

// ---------------- router: logits -> top2 -> per-token (eidx, probs); also emit xbf ----------------
// wave per token; NO atomics.
__global__ void __launch_bounds__(256) router_logits_kernel(
    const float* __restrict__ x, const float* __restrict__ Wn,
    const float* __restrict__ bn, const float* __restrict__ b2,
    ushort_t* __restrict__ xbf, int2* __restrict__ eidx,
    float2* __restrict__ probs, float* __restrict__ out) {
    int wave  = threadIdx.x >> 6;
    int lane  = threadIdx.x & 63;
    int token = blockIdx.x * 4 + wave;
    const float* xr = x + (size_t)token * DIM;
    float acc[NEXP];
#pragma unroll
    for (int e = 0; e < NEXP; ++e) acc[e] = 0.f;
    ushort_t xl[16];
#pragma unroll
    for (int i = 0; i < 16; ++i) {
        int d = lane + i * 64;
        float xv = xr[d];
        xl[i] = f2bf(xv);
        const float4* wr = (const float4*)(Wn + d * NEXP);
        float4 w0 = wr[0], w1 = wr[1], w2 = wr[2], w3 = wr[3];
        acc[0]  += xv * w0.x; acc[1]  += xv * w0.y; acc[2]  += xv * w0.z; acc[3]  += xv * w0.w;
        acc[4]  += xv * w1.x; acc[5]  += xv * w1.y; acc[6]  += xv * w1.z; acc[7]  += xv * w1.w;
        acc[8]  += xv * w2.x; acc[9]  += xv * w2.y; acc[10] += xv * w2.z; acc[11] += xv * w2.w;
        acc[12] += xv * w3.x; acc[13] += xv * w3.y; acc[14] += xv * w3.z; acc[15] += xv * w3.w;
    }
    ushort_t* xbr = xbf + (size_t)token * DIM;
#pragma unroll
    for (int i = 0; i < 16; ++i) xbr[lane + i * 64] = xl[i];
#pragma unroll
    for (int e = 0; e < NEXP; ++e) {
        float v = acc[e];
#pragma unroll
        for (int off = 32; off > 0; off >>= 1) v += __shfl_xor(v, off, 64);
        acc[e] = v + bn[e];
    }
    if (lane == 0) {
        float m0 = -1e30f; int i0 = 0;
        for (int e = 0; e < NEXP; ++e) if (acc[e] > m0) { m0 = acc[e]; i0 = e; }
        float m1 = -1e30f; int i1 = 0;
        for (int e = 0; e < NEXP; ++e) if (e != i0 && acc[e] > m1) { m1 = acc[e]; i1 = e; }
        float tq = expf(m1 - m0);          // m1 <= m0, safe
        float p0 = 1.f / (1.f + tq);
        float p1 = 1.f - p0;
        eidx[token]  = make_int2(i0, i1);
        probs[token] = make_float2(p0, p1);
        out[token]   = p0 * b2[i0] + p1 * b2[i1];
    }
}

// ---------------- bucket build: hist -> scan -> scatter (all parallel, no global atomics) --------
#define NCHUNK 64
#define CHUNK  (N_TOK / NCHUNK)   // 256 tokens per chunk

__global__ void __launch_bounds__(256) hist_kernel(const int2* __restrict__ eidx,
                                                   int* __restrict__ counts) {
    __shared__ int h[NEXP];
    const int t = threadIdx.x;
    if (t < NEXP) h[t] = 0;
    __syncthreads();
    int token = blockIdx.x * CHUNK + t;
    int2 ei = eidx[token];
    atomicAdd(&h[ei.x], 1);
    atomicAdd(&h[ei.y], 1);
    __syncthreads();
    if (t < NEXP) counts[t * NCHUNK + blockIdx.x] = h[t];
}

// 1 block, 1024 threads = 16 waves; wave w = expert w, lane = chunk.
__global__ void __launch_bounds__(1024) scan_kernel(const int* __restrict__ counts,
                                                    int* __restrict__ offs,
                                                    int* __restrict__ cnt) {
    const int w    = threadIdx.x >> 6;
    const int lane = threadIdx.x & 63;
    int v = counts[w * NCHUNK + lane];
    int orig = v;
#pragma unroll
    for (int off = 1; off < 64; off <<= 1) {
        int up = __shfl_up(v, off, 64);
        if (lane >= off) v += up;
    }
    offs[w * NCHUNK + lane] = v - orig;   // exclusive prefix within expert
    if (lane == 63) cnt[w] = v;
}

__global__ void __launch_bounds__(256) scatter_kernel(
    const int2* __restrict__ eidx, const float2* __restrict__ probs,
    const int* __restrict__ offs, int* __restrict__ tok, float* __restrict__ gate) {
    __shared__ int wcnt[4][NEXP];
    const int t = threadIdx.x;
    const int wv = t >> 6, lane = t & 63;
    const int token = blockIdx.x * CHUNK + t;
    int2  ei = eidx[token];
    float2 pr = probs[token];
    unsigned long long lmask = (1ull << lane) - 1ull;
#pragma unroll
    for (int e = 0; e < NEXP; ++e) {
        bool s = (ei.x == e) | (ei.y == e);
        unsigned long long m = __ballot(s);
        if (lane == 0) wcnt[wv][e] = __popcll(m);
    }
    __syncthreads();
#pragma unroll
    for (int e = 0; e < NEXP; ++e) {
        bool s0 = (ei.x == e);
        bool s  = s0 | (ei.y == e);
        unsigned long long m = __ballot(s);
        int base = offs[e * NCHUNK + blockIdx.x];
        for (int w = 0; w < wv; ++w) base += wcnt[w][e];
        int pos = base + __popcll(m & lmask);
        if (s) {
            tok[e * N_TOK + pos]  = token;
            gate[e * N_TOK + pos] = s0 ? pr.x : pr.y;
        }
    }
}

// ---------------- main: gathered expert FFN, bf16 MFMA 128x128xK tile ----------------
// grid: (HID/128, 64, NEXP), block 256
__global__ void __launch_bounds__(256, 2) moe_ffn_kernel(
    const ushort_t* __restrict__ xbf, const ushort_t* __restrict__ w1t,
    const float* __restrict__ b1, const float* __restrict__ w2,
    const int* __restrict__ tok, const float* __restrict__ gate,
    const int* __restrict__ cnt, float* __restrict__ out) {
    __shared__ ushort_t Alds[128 * 64];
    __shared__ ushort_t Blds[128 * 64];
    const int e  = blockIdx.z;
    const int ce = cnt[e];
    const int m0 = blockIdx.y * 128;
    if (m0 >= ce) return;
    const int h0 = blockIdx.x * 128;
    const int t    = threadIdx.x;
    const int wv   = t >> 6;
    const int lane = t & 63;
    const int quad = lane >> 4;
    const int ln   = lane & 15;
    const int wm   = (wv >> 1) * 64;   // wave M offset in tile
    const int wn   = (wv & 1) * 64;    // wave N offset in tile

    // Token ids for the A rows this thread stages (clamped into bucket; m0 < ce)
    int tkid[4];
#pragma unroll
    for (int i = 0; i < 4; ++i) {
        int f = i * 256 + t;
        int r = f >> 3;
        int rr = (m0 + r < ce) ? (m0 + r) : m0;
        tkid[i] = tok[e * N_TOK + rr];
    }

    f32x4 acc[4][4];
    const f32x4 zero = {0.f, 0.f, 0.f, 0.f};
#pragma unroll
    for (int mi = 0; mi < 4; ++mi)
#pragma unroll
        for (int ni = 0; ni < 4; ++ni) acc[mi][ni] = zero;

    for (int k0 = 0; k0 < DIM; k0 += 64) {
        // Stage A(128x64) and B(128x64, rows=h, cols=d) with XOR-swizzled 16B chunks.
        // LDS slot (r*8 + c) holds global k-chunk (c ^ (r&7)) of row r.
#pragma unroll
        for (int i = 0; i < 4; ++i) {
            int f = i * 256 + t;
            int r = f >> 3, c = f & 7;
            int cs = (c ^ (r & 7)) << 3;
            const ushort_t* ga = xbf + (size_t)tkid[i] * DIM + k0 + cs;
            gl_lds16(ga, &Alds[f * 8]);
            const ushort_t* gb = w1t + ((size_t)e * HID + h0 + r) * DIM + k0 + cs;
            gl_lds16(gb, &Blds[f * 8]);
        }
        __syncthreads();
#pragma unroll
        for (int ks = 0; ks < 2; ++ks) {
            int q = ks * 4 + quad;               // k-chunk index within row
            int csw = (q ^ (ln & 7)) << 3;       // swizzled element offset
            bf16x8 af[4], bfr[4];
#pragma unroll
            for (int mi = 0; mi < 4; ++mi)
                af[mi] = *(const bf16x8*)&Alds[(wm + mi * 16 + ln) * 64 + csw];
#pragma unroll
            for (int ni = 0; ni < 4; ++ni)
                bfr[ni] = *(const bf16x8*)&Blds[(wn + ni * 16 + ln) * 64 + csw];
#pragma unroll
            for (int mi = 0; mi < 4; ++mi)
#pragma unroll
                for (int ni = 0; ni < 4; ++ni)
                    acc[mi][ni] = __builtin_amdgcn_mfma_f32_16x16x32_bf16(
                        af[mi], bfr[ni], acc[mi][ni], 0, 0, 0);
        }
        __syncthreads();
    }

    // Epilogue: relu(acc + b1) * w2, reduce over the 64 h-columns this wave owns,
    // then atomicAdd gate*partial into out[token].
#pragma unroll
    for (int mi = 0; mi < 4; ++mi) {
        float part[4] = {0.f, 0.f, 0.f, 0.f};
#pragma unroll
        for (int ni = 0; ni < 4; ++ni) {
            int h = h0 + wn + ni * 16 + ln;
            float bb = b1[e * HID + h];
            float ww = w2[e * HID + h];
#pragma unroll
            for (int rg = 0; rg < 4; ++rg) {
                float v = acc[mi][ni][rg] + bb;
                v = v > 0.f ? v : 0.f;
                part[rg] += v * ww;
            }
        }
#pragma unroll
        for (int rg = 0; rg < 4; ++rg) {
            float v = part[rg];
            v += __shfl_xor(v, 1, 64);
            v += __shfl_xor(v, 2, 64);
            v += __shfl_xor(v, 4, 64);
            v += __shfl_xor(v, 8, 64);
            part[rg] = v;
        }
        if (ln == 0) {
#pragma unroll
            for (int rg = 0; rg < 4; ++rg) {
                int r = m0 + wm + mi * 16 + quad * 4 + rg;
                if (r < ce) {
                    int tk  = tok[e * N_TOK + r];
                    float g = gate[e * N_TOK + r];
                    atomicAdd(&out[tk], g * part[rg]);
                }
            }
        }
    }
}

extern "C" void kernel_launch(void* const* d_in, const int* in_sizes, int n_in,
                              void* d_out, int out_size, void* d_ws, size_t ws_size,
                              hipStream_t stream) {
    (void)in_sizes; (void)n_in; (void)out_size; (void)ws_size;
    const float* x  = (const float*)d_in[0];
    // d_in[1]=Wr, d_in[2]=br are dead in the reference
    const float* Wn = (const float*)d_in[3];
    const float* bn = (const float*)d_in[4];
    const float* W1 = (const float*)d_in[5];
    const float* b1 = (const float*)d_in[6];
    const float* W2 = (const float*)d_in[7];
    const float* b2 = (const float*)d_in[8];
    float* out = (float*)d_out;

    char* ws = (char*)d_ws;
    ushort_t* xbf = (ushort_t*)ws;                                     // 32 MB
    ushort_t* w1t = (ushort_t*)(ws + (size_t)32 * 1024 * 1024);        // 128 MB
    char* p2 = ws + (size_t)160 * 1024 * 1024;
    size_t off = 0;
    int*    tok    = (int*)(p2 + off);    off += (size_t)NEXP * N_TOK * 4;   // 1 MB
    float*  gate   = (float*)(p2 + off);  off += (size_t)NEXP * N_TOK * 4;   // 1 MB
    int*    cnt    = (int*)(p2 + off);    off += 256;
    int2*   eidx   = (int2*)(p2 + off);   off += (size_t)N_TOK * 8;          // 128 KB
    float2* probs  = (float2*)(p2 + off); off += (size_t)N_TOK * 8;          // 128 KB
    int*    counts = (int*)(p2 + off);    off += NEXP * NCHUNK * 4;          // 4 KB
    int*    offs   = (int*)(p2 + off);    off += NEXP * NCHUNK * 4;          // 4 KB

    router_logits_kernel<<<N_TOK / 4, 256, 0, stream>>>(x, Wn, bn, b2, xbf, eidx, probs, out);
    hist_kernel<<<NCHUNK, 256, 0, stream>>>(eidx, counts);
    scan_kernel<<<1, 1024, 0, stream>>>(counts, offs, cnt);
    scatter_kernel<<<NCHUNK, 256, 0, stream>>>(eidx, probs, offs, tok, gate);
    // transpose right before the FFN so w1t is freshest in L3
    transpose_w1_kernel<<<dim3(HID / 64, DIM / 64, NEXP), 256, 0, stream>>>(W1, w1t);
    moe_ffn_kernel<<<dim3(HID / 128, 64, NEXP), 256, 0, stream>>>(xbf, w1t, b1, W2, tok,
                                                                  gate, cnt, out);
}